// Round 3
// baseline (1283.154 us; speedup 1.0000x reference)
//
#include <hip/hip_runtime.h>
#include <hip/hip_cooperative_groups.h>

namespace cg = cooperative_groups;

// Single cooperative-kernel Sinkhorn, factorized into scaling vectors.
//   A = s + EPS; updates: C0(prep), (R,C)x4 fused, R9 fused into output.
//   col update: C[j] = 1/sum_{i<nr} A[i,j]*R[i]
//   row update: R[i] = 1/sum_{j<nc} A[i,j]*C[j]
// H = fp16 A staged in lower half of d_out (L3-resident for middle passes).
// Key fusion: a block owning 64 rows computes R[i] for its rows and the col
// partial sums with that fresh R in the SAME H read -> H read once/iteration,
// R never hits memory. grid.sync() between phases (10 syncs, 1 launch).

#define BB 64
#define NN 1024
#define MM 1024
#define EPS 1e-4f
#define NCHUNK 16              // 64-row chunks per batch
#define NITEM (BB * NCHUNK)    // 1024 row-partition work items

typedef _Float16 half_t;
typedef __attribute__((ext_vector_type(4))) _Float16 half4_t;
typedef __attribute__((ext_vector_type(4))) float float4_t;

__device__ __forceinline__ float wave_sum(float v) {
#pragma unroll
  for (int off = 32; off > 0; off >>= 1) v += __shfl_xor(v, off, 64);
  return v;
}

__global__ __launch_bounds__(256, 4) void sinkhorn_coop(
    const float* __restrict__ s, const int* __restrict__ nrows,
    const int* __restrict__ ncols, half_t* __restrict__ H,
    float* __restrict__ C, float* __restrict__ P, float* __restrict__ out) {
  cg::grid_group grid = cg::this_grid();
  __shared__ float lds[4][MM];  // per-wave col partials (16 KB)
  const int tid = threadIdx.x;
  const int w = tid >> 6, l = tid & 63;

  // ---------- phase 0: prep — H = half(s+eps), col partials (R=1) ----------
  for (int item = blockIdx.x; item < NITEM; item += gridDim.x) {
    int b = item >> 4, chunk = item & 15;
    int nr = nrows[b], nc = ncols[b];
    int rbase = chunk * 64 + w * 16;
    const float* sp = s + (size_t)b * NN * MM;
    half_t* hp = H + (size_t)b * NN * MM;
    float4_t ca[4];
#pragma unroll
    for (int c = 0; c < 4; c++) ca[c] = (float4_t){0.f, 0.f, 0.f, 0.f};
    int nhere = min(nr - rbase, 16);
    for (int rr = 0; rr < nhere; rr++) {
      size_t roff = (size_t)(rbase + rr) * MM;
#pragma unroll
      for (int c = 0; c < 4; c++) {
        if (c * 256 < nc) {
          float4_t v = *(const float4_t*)(sp + roff + c * 256 + l * 4);
          v.x += EPS; v.y += EPS; v.z += EPS; v.w += EPS;
          half4_t h = {(half_t)v.x, (half_t)v.y, (half_t)v.z, (half_t)v.w};
          *(half4_t*)(hp + roff + c * 256 + l * 4) = h;
          ca[c].x += v.x; ca[c].y += v.y; ca[c].z += v.z; ca[c].w += v.w;
        }
      }
    }
    __syncthreads();
#pragma unroll
    for (int c = 0; c < 4; c++) *(float4_t*)&lds[w][c * 256 + l * 4] = ca[c];
    __syncthreads();
    {  // fold 4 waves -> P[chunk][b][:]
      float4_t a0 = *(float4_t*)&lds[0][tid * 4];
      float4_t a1 = *(float4_t*)&lds[1][tid * 4];
      float4_t a2 = *(float4_t*)&lds[2][tid * 4];
      float4_t a3 = *(float4_t*)&lds[3][tid * 4];
      float4_t r;
      r.x = a0.x + a1.x + a2.x + a3.x;
      r.y = a0.y + a1.y + a2.y + a3.y;
      r.z = a0.z + a1.z + a2.z + a3.z;
      r.w = a0.w + a1.w + a2.w + a3.w;
      *(float4_t*)(P + (size_t)(chunk * BB + b) * MM + tid * 4) = r;
    }
    __syncthreads();
  }
  grid.sync();

  // ---------- 4 iterations of fused (row update, col update) ----------
  for (int t = 0; t < 5; t++) {
    // creduce: C[b][j] = (j<nc) ? 1/sum_chunk P : 0
    for (int idx = blockIdx.x * 256 + tid; idx < BB * MM;
         idx += gridDim.x * 256) {
      int b = idx >> 10, j = idx & 1023;
      float s0 = 0.f;
#pragma unroll
      for (int c = 0; c < NCHUNK; c++) s0 += P[(size_t)(c * BB + b) * MM + j];
      C[idx] = (j < ncols[b]) ? 1.f / s0 : 0.f;
    }
    grid.sync();
    if (t == 4) break;  // C8 ready; final phase does R9

    // fused rowcol: per 64-row chunk, R[i] then col partials with fresh R
    for (int item = blockIdx.x; item < NITEM; item += gridDim.x) {
      int b = item >> 4, chunk = item & 15;
      int nr = nrows[b], nc = ncols[b];
      const float* Cb = C + b * MM;
      float4_t cv[4];
#pragma unroll
      for (int c = 0; c < 4; c++)
        cv[c] = *(const float4_t*)(Cb + c * 256 + l * 4);
      float4_t ca[4];
#pragma unroll
      for (int c = 0; c < 4; c++) ca[c] = (float4_t){0.f, 0.f, 0.f, 0.f};
      const half_t* hp = H + (size_t)b * NN * MM;
      int rbase = chunk * 64 + w * 16;
      int nhere = min(nr - rbase, 16);
      for (int rr = 0; rr < nhere; rr++) {
        size_t roff = (size_t)(rbase + rr) * MM;
        float4_t f[4];
        float dot = 0.f;
#pragma unroll
        for (int c = 0; c < 4; c++) {
          if (c * 256 < nc) {
            half4_t h = *(const half4_t*)(hp + roff + c * 256 + l * 4);
            f[c].x = (float)h[0]; f[c].y = (float)h[1];
            f[c].z = (float)h[2]; f[c].w = (float)h[3];
            dot += f[c].x * cv[c].x + f[c].y * cv[c].y + f[c].z * cv[c].z +
                   f[c].w * cv[c].w;
          }
        }
        float r = 1.f / wave_sum(dot);
#pragma unroll
        for (int c = 0; c < 4; c++) {
          if (c * 256 < nc) {
            ca[c].x += f[c].x * r; ca[c].y += f[c].y * r;
            ca[c].z += f[c].z * r; ca[c].w += f[c].w * r;
          }
        }
      }
      __syncthreads();
#pragma unroll
      for (int c = 0; c < 4; c++) *(float4_t*)&lds[w][c * 256 + l * 4] = ca[c];
      __syncthreads();
      {
        float4_t a0 = *(float4_t*)&lds[0][tid * 4];
        float4_t a1 = *(float4_t*)&lds[1][tid * 4];
        float4_t a2 = *(float4_t*)&lds[2][tid * 4];
        float4_t a3 = *(float4_t*)&lds[3][tid * 4];
        float4_t r;
        r.x = a0.x + a1.x + a2.x + a3.x;
        r.y = a0.y + a1.y + a2.y + a3.y;
        r.z = a0.z + a1.z + a2.z + a3.z;
        r.w = a0.w + a1.w + a2.w + a3.w;
        *(float4_t*)(P + (size_t)(chunk * BB + b) * MM + tid * 4) = r;
      }
      __syncthreads();
    }
    grid.sync();
  }

  // ---------- final: R9 from exact fp32 s, out = (s+eps)*C8*R9 ----------
  for (int item = blockIdx.x; item < NITEM; item += gridDim.x) {
    int b = item >> 4, chunk = item & 15;
    int nr = nrows[b], nc = ncols[b];
    const float* Cb = C + b * MM;
    float4_t cv[4];
#pragma unroll
    for (int c = 0; c < 4; c++) cv[c] = *(const float4_t*)(Cb + c * 256 + l * 4);
    int rbase = chunk * 64 + w * 16;
    const float* sp = s + (size_t)b * NN * MM;
    float* op = out + (size_t)b * NN * MM;
    float4_t z = {0.f, 0.f, 0.f, 0.f};
    for (int rr = 0; rr < 16; rr++) {
      int i = rbase + rr;
      size_t roff = (size_t)i * MM;
      if (i < nr) {
        float4_t f[4];
        float dot = 0.f;
#pragma unroll
        for (int c = 0; c < 4; c++) {
          if (c * 256 < nc) {
            float4_t v = *(const float4_t*)(sp + roff + c * 256 + l * 4);
            v.x += EPS; v.y += EPS; v.z += EPS; v.w += EPS;
            f[c] = v;
            dot += v.x * cv[c].x + v.y * cv[c].y + v.z * cv[c].z +
                   v.w * cv[c].w;
          }
        }
        float r = 1.f / wave_sum(dot);
#pragma unroll
        for (int c = 0; c < 4; c++) {
          float4_t o = z;
          if (c * 256 < nc) {
            o.x = f[c].x * cv[c].x * r; o.y = f[c].y * cv[c].y * r;
            o.z = f[c].z * cv[c].z * r; o.w = f[c].w * cv[c].w * r;
          }
          *(float4_t*)(op + roff + c * 256 + l * 4) = o;
        }
      } else {
#pragma unroll
        for (int c = 0; c < 4; c++)
          *(float4_t*)(op + roff + c * 256 + l * 4) = z;
      }
    }
  }
}

extern "C" void kernel_launch(void* const* d_in, const int* in_sizes, int n_in,
                              void* d_out, int out_size, void* d_ws,
                              size_t ws_size, hipStream_t stream) {
  const float* s = (const float*)d_in[0];
  const int* nrows = (const int*)d_in[1];
  const int* ncols = (const int*)d_in[2];
  float* out = (float*)d_out;
  half_t* H = (half_t*)d_out;  // fp16 A in lower 128MB of d_out; dead by the
                               // time final-phase out writes land there
  float* C = (float*)d_ws;     // [BB*MM]
  float* P = C + BB * MM;      // [NCHUNK][BB][MM] partial col sums (4MB)

  int blocksPerCU = 0;
  hipOccupancyMaxActiveBlocksPerMultiprocessor(&blocksPerCU, sinkhorn_coop,
                                               256, 0);
  if (blocksPerCU < 1) blocksPerCU = 1;
  int G = blocksPerCU * 256;  // 256 CUs on MI355X
  if (G > NITEM) G = NITEM;

  void* args[] = {(void*)&s, (void*)&nrows, (void*)&ncols,
                  (void*)&H, (void*)&C,     (void*)&P,     (void*)&out};
  hipLaunchCooperativeKernel(sinkhorn_coop, dim3(G), dim3(256), args, 0,
                             stream);
}